// Round 3
// baseline (482.184 us; speedup 1.0000x reference)
//
#include <hip/hip_runtime.h>
#include <hip/hip_bf16.h>
#include <stdint.h>

typedef __attribute__((ext_vector_type(8))) short short8;
typedef __attribute__((ext_vector_type(4))) short short4v;
typedef __attribute__((ext_vector_type(4))) float floatx4;

#define B_TOT 1024
#define NW_MASK 64

#define MFMA(a, b, c) __builtin_amdgcn_mfma_f32_16x16x32_bf16((a), (b), (c), 0, 0, 0)

// ---- ws layout (bytes) ----
#define WOFF_W    0          // [8 heads][32768]: 7 parts x 16 oc x 132 k bf16 (+pad to 32768)
#define WOFF_WP   262144     // [4 hp][128 n][32 kk] bf16 = 32768
#define WOFF_BIAS 294912     // [8 h][128 n][128 m] fp32 = 524288
#define WOFF_MASK 819200     // [64 wi][128 n][128 m] fp32 = 4194304
// total ~4.8 MB

// ---- LDS layout (bytes) ----
#define L_W   0        // [7][16][132] bf16 staged W (+pad) = 32768
#define L_KP  32768    // [3][128][20] bf16 k splits = 15360
#define L_VS  48128    // [128][17] fp32 v = 8704
#define L_SCR 56832    // 8 waves x 3072: q-parts [3][16][20] @0, xo [16][36] @el 960
#define LDS_TOTAL 81408

__device__ __forceinline__ float bf2f(ushort u) {
  union { uint32_t u; float f; } v; v.u = ((uint32_t)u) << 16; return v.f;
}
__device__ __forceinline__ ushort f2bf(float f) {
  uint32_t u = __float_as_uint(f);
  return (ushort)((u + 0x7FFFu + ((u >> 16) & 1u)) >> 16);  // RNE
}
__device__ __forceinline__ void split3(float f, ushort& h, ushort& m, ushort& l) {
  h = f2bf(f);  float r  = f - bf2f(h);
  m = f2bf(r);  float r2 = r - bf2f(m);
  l = f2bf(r2);
}
__device__ __forceinline__ short8 ld8(const ushort* p) {  // 8B-aligned LDS/global read
  union { short8 v; short4v s[2]; } u;
  u.s[0] = *(const short4v*)p; u.s[1] = *(const short4v*)(p + 4);
  return u.v;
}
__device__ __forceinline__ void gld_lds16(const void* g, void* l) {
  __builtin_amdgcn_global_load_lds((const __attribute__((address_space(1))) unsigned*)g,
                                   (__attribute__((address_space(3))) unsigned*)l, 16, 0, 0);
}

// ---------------------------------------------------------------------------
// Prep: split W, transpose bias/mask. grid 585 x 512.
// ---------------------------------------------------------------------------
__global__ __launch_bounds__(512)
void prep_kernel(const float* __restrict__ mask, const float* __restrict__ Wq,
                 const float* __restrict__ Wkv, const float* __restrict__ Wproj,
                 const float* __restrict__ table, const int* __restrict__ rel_index,
                 char* __restrict__ ws) {
  int b = blockIdx.x, t = threadIdx.x;
  if (b < 64) {              // bias_t[h][n][m] fp32
    int h = b >> 3, n = (b & 7) * 16 + (t >> 5), m4 = (t & 31) * 4;
    float* bt = (float*)(ws + WOFF_BIAS);
    floatx4 v;
    #pragma unroll
    for (int i = 0; i < 4; ++i)
      v[i] = table[rel_index[(m4 + i) * 128 + n] * 8 + h];
    *(floatx4*)(bt + (h * 128 + n) * 128 + m4) = v;
  } else if (b < 576) {      // mask_t[wi][n][m] fp32
    int q = b - 64;
    int wi = q >> 3, n = (q & 7) * 16 + (t >> 5), m4 = (t & 31) * 4;
    float* mt = (float*)(ws + WOFF_MASK);
    floatx4 v;
    #pragma unroll
    for (int i = 0; i < 4; ++i)
      v[i] = mask[wi * 16384 + (m4 + i) * 128 + n];
    *(floatx4*)(mt + ((size_t)wi * 128 + n) * 128 + m4) = v;
  } else if (b < 584) {      // W splits per head: parts 0-2 q(hi,mi,lo)*0.25, 3-5 k, 6 v
    int h = b - 576;
    int oc = t >> 5, k4 = (t & 31) * 4;
    ushort* wh = (ushort*)(ws + WOFF_W) + h * 16384;
    #pragma unroll
    for (int i = 0; i < 4; ++i) {
      int kk = k4 + i;
      int base = oc * 132 + kk;
      ushort a, bb, cc;
      split3(Wq[kk * 128 + h * 16 + oc] * 0.25f, a, bb, cc);
      wh[base] = a; wh[2112 + base] = bb; wh[2 * 2112 + base] = cc;
      split3(Wkv[kk * 256 + h * 16 + oc], a, bb, cc);
      wh[3 * 2112 + base] = a; wh[4 * 2112 + base] = bb; wh[5 * 2112 + base] = cc;
      wh[6 * 2112 + base] = f2bf(Wkv[kk * 256 + 128 + h * 16 + oc]);
    }
  } else {                   // wp[hp][n][kk] bf16
    ushort* wp = (ushort*)(ws + WOFF_WP);
    #pragma unroll
    for (int z = 0; z < 32; ++z) {
      int idx = t * 32 + z;
      int hp = idx >> 12, r = idx & 4095, n = r >> 5, kk = r & 31;
      wp[idx] = f2bf(Wproj[(hp * 32 + kk) * 128 + n]);
    }
  }
}

// ---------------------------------------------------------------------------
// Main: fused window attention. 512 threads = 8 waves, wave w owns rows 16w..+15.
// ---------------------------------------------------------------------------
__global__ __launch_bounds__(512, 2)
void wattn_kernel(const float* __restrict__ x, const float* __restrict__ bproj,
                  const char* __restrict__ ws, float* __restrict__ out) {
  extern __shared__ char smem[];
  ushort* wlds   = (ushort*)(smem + L_W);
  ushort* kparts = (ushort*)(smem + L_KP);
  float*  vs     = (float*)(smem + L_VS);

  const int tid  = threadIdx.x;
  const int w    = tid >> 6;
  const int l    = tid & 63;
  const int quad = l >> 4;
  const int c    = l & 15;
  const int b    = blockIdx.x;
  const int wi   = b & (NW_MASK - 1);
  const bool lo  = quad < 2;

  ushort* scr = (ushort*)(smem + L_SCR) + w * 1536;  // per-wave private

  // ---- load this lane's x row-halves, split once, keep the 2 needed parts
  short8 xA[8], xB[8];   // xA = [xh|xm] halves, xB = [xh|xl] halves (by quad)
  {
    const float* xrow = x + ((size_t)b * 128 + 16 * w + c) * 128 + (quad & 1) * 8;
    #pragma unroll
    for (int kt = 0; kt < 8; ++kt) {
      floatx4 f0 = *(const floatx4*)(xrow + kt * 16);
      floatx4 f1 = *(const floatx4*)(xrow + kt * 16 + 4);
      short8 hh, mm, ll;
      #pragma unroll
      for (int j = 0; j < 8; ++j) {
        float f = (j < 4) ? f0[j] : f1[j - 4];
        ushort a, bb, cc; split3(f, a, bb, cc);
        hh[j] = (short)a; mm[j] = (short)bb; ll[j] = (short)cc;
      }
      xA[kt] = lo ? hh : mm;
      xB[kt] = lo ? hh : ll;
    }
  }

  floatx4 oacc[8];
  #pragma unroll
  for (int j = 0; j < 8; ++j) oacc[j] = (floatx4){0.f, 0.f, 0.f, 0.f};

  const ushort* wsW   = (const ushort*)(ws + WOFF_W);
  const ushort* wsP   = (const ushort*)(ws + WOFF_WP);
  const float* bias_t = (const float*)(ws + WOFF_BIAS);
  const float* mask_t = (const float*)(ws + WOFF_MASK);

  for (int h = 0; h < 8; ++h) {
    // ---- stage W[h] (pre-split) into LDS, 2048 x 16B chunks, zero VALU work
    {
      const ushort* src = wsW + h * 16384;
      #pragma unroll
      for (int it = 0; it < 4; ++it) {
        int chunk = it * 512 + tid;
        gld_lds16(src + chunk * 8, wlds + chunk * 8);
      }
    }
    __syncthreads();

    // ---- phase 2: q^T (A=W,B=x), k and v (A=x,B=W); 6-term split precision
    floatx4 qa = (floatx4){0.f,0.f,0.f,0.f};
    floatx4 ka = (floatx4){0.f,0.f,0.f,0.f};
    floatx4 va = (floatx4){0.f,0.f,0.f,0.f};
    {
      const int wfo = c * 132 + (quad & 1) * 8;
      const ushort* aq1p = wlds + (lo ? 0 : 1) * 2112;
      const ushort* aq2p = wlds + (lo ? 1 : 0) * 2112;
      const ushort* aq3p = wlds + (lo ? 2 : 0) * 2112;
      const ushort* bk3p = wlds + (lo ? 5 : 3) * 2112;
      #pragma unroll
      for (int kt = 0; kt < 8; ++kt) {
        int o = wfo + kt * 16;
        short8 wq1 = ld8(aq1p + o);              // [wh|wm]
        short8 wq2 = ld8(aq2p + o);              // [wm|wh]
        short8 wq3 = ld8(aq3p + o);              // [wl|wh]
        qa = MFMA(wq1, xA[kt], qa);
        qa = MFMA(wq2, xA[kt], qa);
        qa = MFMA(wq3, xB[kt], qa);
        short8 wk1 = ld8(wlds + 3 * 2112 + o);   // [kh|kh]
        short8 wk2 = ld8(wlds + 4 * 2112 + o);   // [km|km]
        short8 wk3 = ld8(bk3p + o);              // [kl|kh]
        ka = MFMA(xA[kt], wk1, ka);
        ka = MFMA(xA[kt], wk2, ka);
        ka = MFMA(xB[kt], wk3, ka);
        short8 wv = ld8(wlds + 6 * 2112 + o);
        va = MFMA(xA[kt], wv, va);
      }
    }
    // store q^T splits (wave-private scratch), k splits + v (shared)
    #pragma unroll
    for (int i = 0; i < 4; ++i) {
      ushort a, bb, cc;
      split3(qa[i], a, bb, cc);
      int qe = c * 20 + 4 * quad + i;       // [tok-local c][hd 4q+i]
      scr[qe] = a; scr[320 + qe] = bb; scr[640 + qe] = cc;
      int tok = 16 * w + 4 * quad + i;
      split3(ka[i], a, bb, cc);
      kparts[tok * 20 + c] = a;
      kparts[2560 + tok * 20 + c] = bb;
      kparts[5120 + tok * 20 + c] = cc;
      vs[tok * 17 + c] = va[i];
    }
    __syncthreads();

    // ---- phase 3: S = q k^T + bias + mask (vectorized [n][m] init)
    floatx4 sacc[8];
    {
      int qo = c * 20 + (quad & 1) * 8;
      short8 aq1 = ld8(scr + (lo ? 0 : 320) + qo);   // [qh|qm]
      short8 aq3 = ld8(scr + (lo ? 0 : 640) + qo);   // [qh|ql]
      const float* bt = bias_t + (size_t)h * 16384;
      const float* mt = mask_t + (size_t)wi * 16384;
      const int mbase = 16 * w + 4 * quad;
      #pragma unroll
      for (int j = 0; j < 8; ++j) {
        int n = 16 * j + c;
        floatx4 bi = *(const floatx4*)(bt + n * 128 + mbase);
        floatx4 ma = *(const floatx4*)(mt + n * 128 + mbase);
        floatx4 acc = bi + ma;
        int ko = n * 20 + (quad & 1) * 8;
        short8 b1 = ld8(kparts + ko);
        short8 b2 = ld8(kparts + 2560 + ko);
        short8 b3 = ld8(kparts + (lo ? 5120 : 0) + ko);
        acc = MFMA(aq1, b1, acc);
        acc = MFMA(aq1, b2, acc);
        acc = MFMA(aq3, b3, acc);
        sacc[j] = acc;
      }
    }

    // ---- phase 3b: register softmax denom + top-2 + weighted V gather
    #pragma unroll
    for (int i = 0; i < 4; ++i) {
      float m1 = sacc[0][i]; int i1 = c;
      float m2 = -__builtin_inff(); int i2 = -1;
      float psum = 1.0f;
      #pragma unroll
      for (int j = 1; j < 8; ++j) {
        float v = sacc[j][i]; int col = 16 * j + c;
        bool g1 = v > m1;
        float e = __expf(g1 ? (m1 - v) : (v - m1));
        psum = g1 ? (psum * e + 1.0f) : (psum + e);
        bool g2 = (!g1) && (v > m2);
        m2 = g1 ? m1 : (g2 ? v : m2);
        i2 = g1 ? i1 : (g2 ? col : i2);
        m1 = g1 ? v : m1;
        i1 = g1 ? col : i1;
      }
      #pragma unroll
      for (int d = 1; d < 16; d <<= 1) {
        float om1 = __shfl_xor(m1, d); int oi1 = __shfl_xor(i1, d);
        float om2 = __shfl_xor(m2, d); int oi2 = __shfl_xor(i2, d);
        float ops = __shfl_xor(psum, d);
        bool aw = (m1 > om1) || (m1 == om1 && i1 < oi1);
        float M  = aw ? m1 : om1;  int I  = aw ? i1 : oi1;
        float lv = aw ? om1 : m1;  int li = aw ? oi1 : i1;
        float sv = aw ? m2 : om2;  int si = aw ? i2 : oi2;
        bool sb = (sv > lv) || (sv == lv && si < li);
        float e = __expf(lv - M);
        psum = (aw ? psum : ops) + (aw ? ops : psum) * e;
        m1 = M; i1 = I;
        m2 = sb ? sv : lv; i2 = sb ? si : li;
      }
      float p1 = 1.0f / psum;
      float p2 = __expf(m2 - m1) * p1;
      float o = p1 * vs[i1 * 17 + c] + p2 * vs[i2 * 17 + c];
      scr[960 + (4 * quad + i) * 36 + (h & 1) * 16 + c] = f2bf(o);  // xo C-layout
    }

    // ---- phase 4: out-projection per head pair (K=32), B-frags from global
    if (h & 1) {
      short8 axo = ld8(scr + 960 + c * 36 + quad * 8);
      const ushort* wpp = wsP + (h >> 1) * 4096;
      #pragma unroll
      for (int j = 0; j < 8; ++j) {
        short8 bf = *(const short8*)(wpp + (16 * j + c) * 32 + quad * 8);
        oacc[j] = MFMA(axo, bf, oacc[j]);
      }
    }
    __syncthreads();
  }

  // ---- epilogue: + bproj, fp32 store
  #pragma unroll
  for (int j = 0; j < 8; ++j) {
    float bp = bproj[16 * j + c];
    #pragma unroll
    for (int i = 0; i < 4; ++i) {
      int row = 16 * w + 4 * quad + i;
      out[((size_t)b * 128 + row) * 128 + 16 * j + c] = oacc[j][i] + bp;
    }
  }
}

extern "C" void kernel_launch(void* const* d_in, const int* in_sizes, int n_in,
                              void* d_out, int out_size, void* d_ws, size_t ws_size,
                              hipStream_t stream) {
  const float* x     = (const float*)d_in[0];
  const float* mask  = (const float*)d_in[1];
  const float* Wq    = (const float*)d_in[2];
  const float* Wkv   = (const float*)d_in[3];
  const float* Wproj = (const float*)d_in[4];
  const float* bproj = (const float*)d_in[5];
  const float* btab  = (const float*)d_in[6];
  const int*   ridx  = (const int*)d_in[7];
  float* outp = (float*)d_out;
  char*  ws   = (char*)d_ws;

  (void)in_sizes; (void)n_in; (void)out_size; (void)ws_size;

  hipFuncSetAttribute(reinterpret_cast<const void*>(wattn_kernel),
                      hipFuncAttributeMaxDynamicSharedMemorySize, LDS_TOTAL);

  prep_kernel<<<585, 512, 0, stream>>>(mask, Wq, Wkv, Wproj, btab, ridx, ws);
  wattn_kernel<<<B_TOT, 512, LDS_TOTAL, stream>>>(x, bproj, ws, outp);
}